// Round 15
// baseline (251.351 us; speedup 1.0000x reference)
//
#include <hip/hip_runtime.h>
#include <cstdint>
#include <cstddef>

// Problem constants
#define B_N   16384
#define D_DIM 16
#define K_NBR 25
#define CAP   256       // per-row LDS candidate capacity (E[C]~96)
#define MAXL  4         // CAP/64
#define NSAMP 1024      // threshold sample count per row
#define EPAD  20        // u16 row pad for eig staging buffers
#define NPART (B_N / 4) // per-block partials from eig (4096)

// Workspace: accum | sq | T | rawh | rawl | lath | latl | nbrG | part
#define WS_SQ_OFF   256
#define WS_T_OFF    (WS_SQ_OFF + 65536)
#define WS_RAWH_OFF (WS_T_OFF + 65536)
#define WS_RAWL_OFF (WS_RAWH_OFF + B_N * D_DIM * 2)
#define WS_LATH_OFF (WS_RAWL_OFF + B_N * D_DIM * 2)
#define WS_LATL_OFF (WS_LATH_OFF + B_N * D_DIM * 2)
#define WS_NBR_OFF  (WS_LATL_OFF + B_N * D_DIM * 2)
#define WS_PART_OFF (WS_NBR_OFF + B_N * K_NBR * 4)

typedef __attribute__((ext_vector_type(8))) short bf16x8;
typedef __attribute__((ext_vector_type(4))) float f32x4;

__device__ __forceinline__ unsigned map_f32(float x) {
    unsigned u = __float_as_uint(x);
    return (u & 0x80000000u) ? ~u : (u | 0x80000000u); // order-preserving
}

__device__ __forceinline__ unsigned short f2bf(float x) {   // RNE f32->bf16 bits
    unsigned u = __float_as_uint(x);
    unsigned r = (u + 0x7FFFu + ((u >> 16) & 1u)) >> 16;
    return (unsigned short)r;
}
__device__ __forceinline__ float bf2f(unsigned short h) {
    return __uint_as_float(((unsigned)h) << 16);
}

// ---------------------------------------------------------------- prep: sq + recon + bf16 hi/lo splits
__global__ __launch_bounds__(256) void prep_kernel(const float4* __restrict__ rawv,
                                                   const float4* __restrict__ latv,
                                                   const float4* __restrict__ ov,
                                                   const float4* __restrict__ tv,
                                                   float* __restrict__ sq,
                                                   unsigned short* __restrict__ rawh,
                                                   unsigned short* __restrict__ rawl,
                                                   unsigned short* __restrict__ lath,
                                                   unsigned short* __restrict__ latl,
                                                   float* __restrict__ accum) {
    int i = blockIdx.x * 256 + threadIdx.x;
    float v[16];
    {
        float4 r0 = rawv[i*4+0], r1 = rawv[i*4+1], r2 = rawv[i*4+2], r3 = rawv[i*4+3];
        v[0]=r0.x; v[1]=r0.y; v[2]=r0.z; v[3]=r0.w;
        v[4]=r1.x; v[5]=r1.y; v[6]=r1.z; v[7]=r1.w;
        v[8]=r2.x; v[9]=r2.y; v[10]=r2.z; v[11]=r2.w;
        v[12]=r3.x; v[13]=r3.y; v[14]=r3.z; v[15]=r3.w;
    }
    float s = 0.0f;
    unsigned short h[16], l[16];
    #pragma unroll
    for (int k = 0; k < 16; ++k) {
        s = fmaf(v[k], v[k], s);
        unsigned short hh = f2bf(v[k]);
        h[k] = hh;
        l[k] = f2bf(v[k] - bf2f(hh));
    }
    sq[i] = s;
    #pragma unroll
    for (int q = 0; q < 4; ++q) {
        ((ushort4*)(rawh + (size_t)i*16))[q] = make_ushort4(h[q*4], h[q*4+1], h[q*4+2], h[q*4+3]);
        ((ushort4*)(rawl + (size_t)i*16))[q] = make_ushort4(l[q*4], l[q*4+1], l[q*4+2], l[q*4+3]);
    }
    // latent split
    {
        float4 r0 = latv[i*4+0], r1 = latv[i*4+1], r2 = latv[i*4+2], r3 = latv[i*4+3];
        v[0]=r0.x; v[1]=r0.y; v[2]=r0.z; v[3]=r0.w;
        v[4]=r1.x; v[5]=r1.y; v[6]=r1.z; v[7]=r1.w;
        v[8]=r2.x; v[9]=r2.y; v[10]=r2.z; v[11]=r2.w;
        v[12]=r3.x; v[13]=r3.y; v[14]=r3.z; v[15]=r3.w;
        #pragma unroll
        for (int k = 0; k < 16; ++k) {
            unsigned short hh = f2bf(v[k]);
            h[k] = hh;
            l[k] = f2bf(v[k] - bf2f(hh));
        }
        #pragma unroll
        for (int q = 0; q < 4; ++q) {
            ((ushort4*)(lath + (size_t)i*16))[q] = make_ushort4(h[q*4], h[q*4+1], h[q*4+2], h[q*4+3]);
            ((ushort4*)(latl + (size_t)i*16))[q] = make_ushort4(l[q*4], l[q*4+1], l[q*4+2], l[q*4+3]);
        }
    }

    float rs = 0.0f;
    #pragma unroll
    for (int q = 0; q < 4; ++q) {
        float4 o = ov[i*4+q], t = tv[i*4+q];
        float d;
        d = o.x - t.x; rs = fmaf(d, d, rs);
        d = o.y - t.y; rs = fmaf(d, d, rs);
        d = o.z - t.z; rs = fmaf(d, d, rs);
        d = o.w - t.w; rs = fmaf(d, d, rs);
    }
    #pragma unroll
    for (int off = 32; off >= 1; off >>= 1) rs += __shfl_down(rs, off, 64);
    if ((threadIdx.x & 63) == 0) atomicAdd(&accum[0], rs);   // 256 atomics total: negligible
}

// ---------------------------------------------------------------- per-row distance threshold, LDS-staged
__global__ __launch_bounds__(256) void thresh_kernel(const float4* __restrict__ rawv,
                                                     const unsigned short* __restrict__ rawh,
                                                     const float* __restrict__ sq,
                                                     float* __restrict__ T) {
    __shared__ unsigned short sampH[NSAMP * 16];
    __shared__ float sampSq[NSAMP];
    __shared__ float V[16][48];

    int tid = threadIdx.x;
    for (int s = tid; s < NSAMP; s += 256) {
        int js = s << 4;
        const uint4* src = (const uint4*)(rawh + (size_t)js * 16);
        ((uint4*)(sampH + s * 16))[0] = src[0];
        ((uint4*)(sampH + s * 16))[1] = src[1];
        sampSq[s] = sq[js];
    }

    int rl   = tid >> 4;
    int sidx = tid & 15;
    int i = blockIdx.x * 16 + rl;

    float a[16];
    {
        float4 r0 = rawv[i*4+0], r1 = rawv[i*4+1], r2 = rawv[i*4+2], r3 = rawv[i*4+3];
        a[0]=r0.x; a[1]=r0.y; a[2]=r0.z; a[3]=r0.w;
        a[4]=r1.x; a[5]=r1.y; a[6]=r1.z; a[7]=r1.w;
        a[8]=r2.x; a[9]=r2.y; a[10]=r2.z; a[11]=r2.w;
        a[12]=r3.x; a[13]=r3.y; a[14]=r3.z; a[15]=r3.w;
    }
    float sqi = sq[i];
    __syncthreads();

    float s0 = 3e37f, s1 = 3e37f, s2 = 3e37f;
    for (int t = 0; t < NSAMP / 16; ++t) {
        int s = t * 16 + sidx;
        const uint4* bp = (const uint4*)(sampH + s * 16);
        uint4 h0 = bp[0], h1 = bp[1];
        float dot = 0.0f;
        unsigned w;
        w = h0.x; dot = fmaf(a[0],  __uint_as_float(w << 16), dot); dot = fmaf(a[1],  __uint_as_float(w & 0xFFFF0000u), dot);
        w = h0.y; dot = fmaf(a[2],  __uint_as_float(w << 16), dot); dot = fmaf(a[3],  __uint_as_float(w & 0xFFFF0000u), dot);
        w = h0.z; dot = fmaf(a[4],  __uint_as_float(w << 16), dot); dot = fmaf(a[5],  __uint_as_float(w & 0xFFFF0000u), dot);
        w = h0.w; dot = fmaf(a[6],  __uint_as_float(w << 16), dot); dot = fmaf(a[7],  __uint_as_float(w & 0xFFFF0000u), dot);
        w = h1.x; dot = fmaf(a[8],  __uint_as_float(w << 16), dot); dot = fmaf(a[9],  __uint_as_float(w & 0xFFFF0000u), dot);
        w = h1.y; dot = fmaf(a[10], __uint_as_float(w << 16), dot); dot = fmaf(a[11], __uint_as_float(w & 0xFFFF0000u), dot);
        w = h1.z; dot = fmaf(a[12], __uint_as_float(w << 16), dot); dot = fmaf(a[13], __uint_as_float(w & 0xFFFF0000u), dot);
        w = h1.w; dot = fmaf(a[14], __uint_as_float(w << 16), dot); dot = fmaf(a[15], __uint_as_float(w & 0xFFFF0000u), dot);
        float cur = sqi + sampSq[s] - 2.0f * dot;
        float lo;
        lo = fminf(s0, cur); cur = fmaxf(s0, cur); s0 = lo;
        lo = fminf(s1, cur); cur = fmaxf(s1, cur); s1 = lo;
        lo = fminf(s2, cur); cur = fmaxf(s2, cur); s2 = lo;
    }

    V[rl][sidx*3+0] = s0; V[rl][sidx*3+1] = s1; V[rl][sidx*3+2] = s2;
    __syncthreads();

    int cl0 = 0, cq0 = 0, cl1 = 0, cq1 = 0, cl2 = 0, cq2 = 0;
    for (int k = 0; k < 48; ++k) {
        float v = V[rl][k];
        cl0 += (v < s0); cq0 += (v <= s0);
        cl1 += (v < s1); cq1 += (v <= s1);
        cl2 += (v < s2); cq2 += (v <= s2);
    }
    if (cl0 <= 5 && 5 < cq0) T[i] = s0 + 0.05f;
    else if (cl1 <= 5 && 5 < cq1) T[i] = s1 + 0.05f;
    else if (cl2 <= 5 && 5 < cq2) T[i] = s2 + 0.05f;
}

// ---------------------------------------------------------------- MFMA scan + select: 32 rows/block, 1024 thr
// R14 post-mortem: 512 blocks x 8 waves = 16 waves/CU capped occupancy at 39%. Now 16 waves/block
// -> 8192 waves = 32/CU; 2 blocks/CU x 36.3 KB LDS = 72.6 KB (fits); VGPR 44 < 128 cap of a
// 16-wave block. NOTE: plain __launch_bounds__ only — a second argument caused a 64-VGPR cap +
// unified-AGPR split and massive scratch spill on gfx950 (R7/R8). Do not add it.
__global__ __launch_bounds__(1024) void scan_kernel(const unsigned short* __restrict__ rawh,
                                                    const unsigned short* __restrict__ rawl,
                                                    const float* __restrict__ sq,
                                                    const float* __restrict__ T,
                                                    unsigned* __restrict__ nbrG) {
    __shared__ unsigned keyS[32 * CAP];
    __shared__ int      cntS[32];
    __shared__ int      nbrW[32][K_NBR];

    int tid  = threadIdx.x;
    int wave = tid >> 6;       // 0..15
    int lane = tid & 63;
    int quad = lane >> 4;
    int lnib = lane & 15;
    int i0   = blockIdx.x * 32;
    int koff = (quad & 1) * 8;

    if (tid < 32) cntS[tid] = 0;

    const unsigned short* ab = (quad < 2 ? rawh : rawl) + (size_t)(i0 + lnib) * 16 + koff;
    bf16x8 afrag0 = *(const bf16x8*)ab;
    bf16x8 afrag1 = *(const bf16x8*)(ab + 16 * 16);

    float sqi[8], hcut[8];
    #pragma unroll
    for (int r = 0; r < 4; ++r) {
        int m = quad * 4 + r;
        sqi[r]     = sq[i0 + m];
        hcut[r]    = 0.5f * (sqi[r] - T[i0 + m]);
        sqi[4+r]   = sq[i0 + m + 16];
        hcut[4+r]  = 0.5f * (sqi[4+r] - T[i0 + m + 16]);
    }
    __syncthreads();

    // ---- phase 1: 1024 j-tiles over 16 waves, 2-tile ILP (pairs t, t+16)
    for (int t = wave; t < B_N / 16; t += 32) {
        int jA = t * 16 + lnib;
        int jB = jA + 256;            // tile t+16
        bf16x8 bhA = *(const bf16x8*)(rawh + (size_t)jA * 16 + koff);
        bf16x8 blA = *(const bf16x8*)(rawl + (size_t)jA * 16 + koff);
        bf16x8 bhB = *(const bf16x8*)(rawh + (size_t)jB * 16 + koff);
        bf16x8 blB = *(const bf16x8*)(rawl + (size_t)jB * 16 + koff);
        float sqjA = sq[jA];
        float sqjB = sq[jB];
        f32x4 a0A = {0,0,0,0}, a1A = {0,0,0,0}, a0B = {0,0,0,0}, a1B = {0,0,0,0};
        a0A = __builtin_amdgcn_mfma_f32_16x16x32_bf16(afrag0, blA, a0A, 0, 0, 0);
        a1A = __builtin_amdgcn_mfma_f32_16x16x32_bf16(afrag1, blA, a1A, 0, 0, 0);
        a0B = __builtin_amdgcn_mfma_f32_16x16x32_bf16(afrag0, blB, a0B, 0, 0, 0);
        a1B = __builtin_amdgcn_mfma_f32_16x16x32_bf16(afrag1, blB, a1B, 0, 0, 0);
        a0A = __builtin_amdgcn_mfma_f32_16x16x32_bf16(afrag0, bhA, a0A, 0, 0, 0);
        a1A = __builtin_amdgcn_mfma_f32_16x16x32_bf16(afrag1, bhA, a1A, 0, 0, 0);
        a0B = __builtin_amdgcn_mfma_f32_16x16x32_bf16(afrag0, bhB, a0B, 0, 0, 0);
        a1B = __builtin_amdgcn_mfma_f32_16x16x32_bf16(afrag1, bhB, a1B, 0, 0, 0);
        #pragma unroll
        for (int r = 0; r < 4; ++r) {
            int m0 = quad * 4 + r, m1 = m0 + 16;
            if ((a0A[r] > fmaf(0.5f, sqjA, hcut[r])) && (jA != i0 + m0)) {
                float d2 = sqi[r] + sqjA - 2.0f * a0A[r];
                int pos = atomicAdd(&cntS[m0], 1);
                if (pos < CAP) keyS[m0 * CAP + pos] = (map_f32(d2) & 0xFFFF0000u) | (unsigned)jA;
            }
            if ((a1A[r] > fmaf(0.5f, sqjA, hcut[4+r])) && (jA != i0 + m1)) {
                float d2 = sqi[4+r] + sqjA - 2.0f * a1A[r];
                int pos = atomicAdd(&cntS[m1], 1);
                if (pos < CAP) keyS[m1 * CAP + pos] = (map_f32(d2) & 0xFFFF0000u) | (unsigned)jA;
            }
            if ((a0B[r] > fmaf(0.5f, sqjB, hcut[r])) && (jB != i0 + m0)) {
                float d2 = sqi[r] + sqjB - 2.0f * a0B[r];
                int pos = atomicAdd(&cntS[m0], 1);
                if (pos < CAP) keyS[m0 * CAP + pos] = (map_f32(d2) & 0xFFFF0000u) | (unsigned)jB;
            }
            if ((a1B[r] > fmaf(0.5f, sqjB, hcut[4+r])) && (jB != i0 + m1)) {
                float d2 = sqi[4+r] + sqjB - 2.0f * a1B[r];
                int pos = atomicAdd(&cntS[m1], 1);
                if (pos < CAP) keyS[m1 * CAP + pos] = (map_f32(d2) & 0xFFFF0000u) | (unsigned)jB;
            }
        }
    }
    __syncthreads();

    // ---- phase 2: 16 waves x 2 rows: bisection select + ballot-prefix collect
    unsigned long long ltm = (1ull << lane) - 1ull;
    for (int rr = 0; rr < 2; ++rr) {
        int m  = wave * 2 + rr;
        int pt = i0 + m;
        int C = cntS[m]; C = C < CAP ? C : CAP;
        unsigned kl[MAXL];
        #pragma unroll
        for (int tt = 0; tt < MAXL; ++tt) {
            int c = tt * 64 + lane;
            kl[tt] = (c < C) ? keyS[m * CAP + c] : 0xFFFFFFFFu;
        }
        unsigned lo = 0, hi = 0xFFFFFFFEu;
        for (int it = 0; it < 32 && lo < hi; ++it) {
            unsigned mid = lo + ((hi - lo) >> 1);
            unsigned cc = 0;
            #pragma unroll
            for (int tt = 0; tt < MAXL; ++tt)
                cc += (unsigned)__builtin_popcountll(__ballot(kl[tt] <= mid));
            if (cc >= K_NBR) hi = mid; else lo = mid + 1;
        }
        unsigned T25 = hi;

        int base = 0;
        #pragma unroll
        for (int tt = 0; tt < MAXL; ++tt) {
            bool c = kl[tt] <= T25;
            unsigned long long mk = __ballot(c);
            if (c) {
                int pos = base + __builtin_popcountll(mk & ltm);
                if (pos < K_NBR) nbrW[m][pos] = (int)(kl[tt] & 0xFFFFu);
            }
            base += __builtin_popcountll(mk);
        }
        if (lane == 0) {
            int got = base < K_NBR ? base : K_NBR;
            int pad = (got > 0) ? nbrW[m][0] : pt;
            for (int q = got; q < K_NBR; ++q) nbrW[m][q] = pad;
        }
        if (lane < K_NBR) nbrG[(size_t)pt * K_NBR + lane] = (unsigned)nbrW[m][lane];
    }
}

// ---------------------------------------------------------------- eig v6: MFMA trace; per-block partial (NO global atomic)
__global__ __launch_bounds__(256) void eig_kernel(const unsigned short* __restrict__ lath,
                                                  const unsigned short* __restrict__ latl,
                                                  const unsigned short* __restrict__ rawh,
                                                  const unsigned short* __restrict__ rawl,
                                                  const unsigned* __restrict__ nbrG,
                                                  float* __restrict__ part) {
    __shared__ unsigned short MS[4][2][2][32 * EPAD];  // [wave][comm][h/l]; rows 25..31 zeroed
    __shared__ unsigned short CH[4][2][32 * EPAD];     // [wave][comm]; rows 0..15 hi, 16..31 lo
    __shared__ float psum[4];

    int wave = threadIdx.x >> 6;
    int lane = threadIdx.x & 63;
    int quad = lane >> 4;
    int lnib = lane & 15;
    int pt   = blockIdx.x * 4 + wave;

    {
        int comm = lane >> 5;
        int row  = lane & 31;
        uint2* dh = (uint2*)&MS[wave][comm][0][row * EPAD];
        uint2* dl = (uint2*)&MS[wave][comm][1][row * EPAD];
        if (row < K_NBR) {
            int n = (int)nbrG[(size_t)pt * K_NBR + row];
            const uint2* sh = (const uint2*)((comm ? rawh : lath) + (size_t)n * 16);
            const uint2* sl = (const uint2*)((comm ? rawl : latl) + (size_t)n * 16);
            dh[0] = sh[0]; dh[1] = sh[1]; dh[2] = sh[2]; dh[3] = sh[3];
            dl[0] = sl[0]; dl[1] = sl[1]; dl[2] = sl[2]; dl[3] = sl[3];
        } else {
            uint2 z = make_uint2(0u, 0u);
            dh[0] = z; dh[1] = z; dh[2] = z; dh[3] = z;
            dl[0] = z; dl[1] = z; dl[2] = z; dl[3] = z;
        }
    }
    __syncthreads();

    bf16x8 ones;
    #pragma unroll
    for (int j = 0; j < 8; ++j) ones[j] = (short)0x3F80;

    const unsigned short* Mzh = &MS[wave][0][0][0];
    const unsigned short* Mzl = &MS[wave][0][1][0];
    const unsigned short* Mxh = &MS[wave][1][0][0];
    const unsigned short* Mxl = &MS[wave][1][1][0];

    bf16x8 fzh, fzl, fxh, fxl;
    #pragma unroll
    for (int j = 0; j < 8; ++j) {
        int k = quad * 8 + j;
        fzh[j] = (short)Mzh[k * EPAD + lnib];
        fzl[j] = (short)Mzl[k * EPAD + lnib];
        fxh[j] = (short)Mxh[k * EPAD + lnib];
        fxl[j] = (short)Mxl[k * EPAD + lnib];
    }

    f32x4 mz = {0.f,0.f,0.f,0.f}, mx = {0.f,0.f,0.f,0.f};
    mz = __builtin_amdgcn_mfma_f32_16x16x32_bf16(fzh, fzh, mz, 0, 0, 0);
    mx = __builtin_amdgcn_mfma_f32_16x16x32_bf16(fxh, fxh, mx, 0, 0, 0);
    mz = __builtin_amdgcn_mfma_f32_16x16x32_bf16(fzh, fzl, mz, 0, 0, 0);
    mx = __builtin_amdgcn_mfma_f32_16x16x32_bf16(fxh, fxl, mx, 0, 0, 0);
    mz = __builtin_amdgcn_mfma_f32_16x16x32_bf16(fzl, fzh, mz, 0, 0, 0);
    mx = __builtin_amdgcn_mfma_f32_16x16x32_bf16(fxl, fxh, mx, 0, 0, 0);
    f32x4 dz1 = {0.f,0.f,0.f,0.f}, dx1 = {0.f,0.f,0.f,0.f};
    dz1 = __builtin_amdgcn_mfma_f32_16x16x32_bf16(fzh, ones, dz1, 0, 0, 0);
    dx1 = __builtin_amdgcn_mfma_f32_16x16x32_bf16(fxh, ones, dx1, 0, 0, 0);
    dz1 = __builtin_amdgcn_mfma_f32_16x16x32_bf16(fzl, ones, dz1, 0, 0, 0);
    dx1 = __builtin_amdgcn_mfma_f32_16x16x32_bf16(fxl, ones, dx1, 0, 0, 0);
    f32x4 dz2 = {0.f,0.f,0.f,0.f}, dx2 = {0.f,0.f,0.f,0.f};
    dz2 = __builtin_amdgcn_mfma_f32_16x16x32_bf16(ones, fzh, dz2, 0, 0, 0);
    dx2 = __builtin_amdgcn_mfma_f32_16x16x32_bf16(ones, fxh, dx2, 0, 0, 0);
    dz2 = __builtin_amdgcn_mfma_f32_16x16x32_bf16(ones, fzl, dz2, 0, 0, 0);
    dx2 = __builtin_amdgcn_mfma_f32_16x16x32_bf16(ones, fxl, dx2, 0, 0, 0);

    f32x4 az, ax;
    #pragma unroll
    for (int r = 0; r < 4; ++r) {
        az[r] = mz[r] - dz1[r] * dz2[r] * 0.04f;
        ax[r] = mx[r] - dx1[r] * dx2[r] * 0.04f;
    }

    bool dg = (quad == (lnib >> 2));

    {
        float tz = dg ? az[lnib & 3] : 0.0f;
        float tx = dg ? ax[lnib & 3] : 0.0f;
        #pragma unroll
        for (int off = 1; off < 64; off <<= 1) {
            tz += __shfl_xor(tz, off, 64);
            tx += __shfl_xor(tx, off, 64);
        }
        float iz = 1.0f / fmaxf(tz, 1e-30f), ix = 1.0f / fmaxf(tx, 1e-30f);
        #pragma unroll
        for (int r = 0; r < 4; ++r) { az[r] *= iz; ax[r] *= ix; }
    }

    unsigned short* Bz = &CH[wave][0][0];
    unsigned short* Bx = &CH[wave][1][0];
    for (int s = 0; s < 6; ++s) {
        #pragma unroll
        for (int r = 0; r < 4; ++r) {
            int row = quad * 4 + r;
            unsigned short zh = f2bf(az[r]);
            unsigned short xh = f2bf(ax[r]);
            Bz[row * EPAD + lnib]        = zh;
            Bx[row * EPAD + lnib]        = xh;
            Bz[(row + 16) * EPAD + lnib] = f2bf(az[r] - bf2f(zh));
            Bx[(row + 16) * EPAD + lnib] = f2bf(ax[r] - bf2f(xh));
        }
        bf16x8 fz, gz, fx, gx;
        #pragma unroll
        for (int j = 0; j < 8; ++j) {
            int k  = quad * 8 + j;
            int ks = (k + 16) & 31;
            fz[j] = (short)Bz[k  * EPAD + lnib];
            gz[j] = (short)Bz[ks * EPAD + lnib];
            fx[j] = (short)Bx[k  * EPAD + lnib];
            gx[j] = (short)Bx[ks * EPAD + lnib];
        }
        f32x4 nz = {0.f,0.f,0.f,0.f}, nx = {0.f,0.f,0.f,0.f};
        nz = __builtin_amdgcn_mfma_f32_16x16x32_bf16(fz, fz, nz, 0, 0, 0);
        nx = __builtin_amdgcn_mfma_f32_16x16x32_bf16(fx, fx, nx, 0, 0, 0);
        nz = __builtin_amdgcn_mfma_f32_16x16x32_bf16(fz, gz, nz, 0, 0, 0);
        nx = __builtin_amdgcn_mfma_f32_16x16x32_bf16(fx, gx, nx, 0, 0, 0);
        if (s == 2) {
            float tz = dg ? nz[lnib & 3] : 0.0f;
            float tx = dg ? nx[lnib & 3] : 0.0f;
            #pragma unroll
            for (int off = 1; off < 64; off <<= 1) {
                tz += __shfl_xor(tz, off, 64);
                tx += __shfl_xor(tx, off, 64);
            }
            float iz = 1.0f / fmaxf(tz, 1e-30f), ix = 1.0f / fmaxf(tx, 1e-30f);
            #pragma unroll
            for (int r = 0; r < 4; ++r) { az[r] = nz[r] * iz; ax[r] = nx[r] * ix; }
        } else {
            #pragma unroll
            for (int r = 0; r < 4; ++r) { az[r] = nz[r]; ax[r] = nx[r]; }
        }
    }

    float tz = dg ? az[lnib & 3] : 0.0f;
    float tx = dg ? ax[lnib & 3] : 0.0f;
    float dt = az[0]*ax[0] + az[1]*ax[1] + az[2]*ax[2] + az[3]*ax[3];
    #pragma unroll
    for (int off = 1; off < 64; off <<= 1) {
        tz += __shfl_xor(tz, off, 64);
        tx += __shfl_xor(tx, off, 64);
        dt += __shfl_xor(dt, off, 64);
    }
    if (lane == 0) psum[wave] = dt / fmaxf(tz * tx, 1e-30f);
    __syncthreads();
    if (threadIdx.x == 0)
        part[blockIdx.x] = psum[0] + psum[1] + psum[2] + psum[3];   // plain store, no atomic
}

// ---------------------------------------------------------------- final: reduce partials + combine
__global__ __launch_bounds__(256) void final_kernel(const float* __restrict__ accum,
                                                    const float* __restrict__ part,
                                                    float* __restrict__ out) {
    __shared__ float ws[4];
    int tid = threadIdx.x;
    float s = 0.0f;
    for (int i = tid; i < NPART; i += 256) s += part[i];
    #pragma unroll
    for (int off = 32; off >= 1; off >>= 1) s += __shfl_down(s, off, 64);
    if ((tid & 63) == 0) ws[tid >> 6] = s;
    __syncthreads();
    if (tid == 0) {
        float dot2  = ws[0] + ws[1] + ws[2] + ws[3];
        float recon = accum[0] * (1.0f / (float)(B_N * D_DIM));
        float tsa   = 2.0f - 2.0f * (dot2 * (1.0f / (float)B_N));
        out[0] = recon + 0.1f * tsa;
    }
}

extern "C" void kernel_launch(void* const* d_in, const int* in_sizes, int n_in,
                              void* d_out, int out_size, void* d_ws, size_t ws_size,
                              hipStream_t stream) {
    const float* outputs = (const float*)d_in[0];
    const float* targets = (const float*)d_in[1];
    const float* latent  = (const float*)d_in[2];
    const float* raw     = (const float*)d_in[3];

    float* accum         = (float*)d_ws;
    float* sq            = (float*)((char*)d_ws + WS_SQ_OFF);
    float* T             = (float*)((char*)d_ws + WS_T_OFF);
    unsigned short* rawh = (unsigned short*)((char*)d_ws + WS_RAWH_OFF);
    unsigned short* rawl = (unsigned short*)((char*)d_ws + WS_RAWL_OFF);
    unsigned short* lath = (unsigned short*)((char*)d_ws + WS_LATH_OFF);
    unsigned short* latl = (unsigned short*)((char*)d_ws + WS_LATL_OFF);
    unsigned* nbrG       = (unsigned*)((char*)d_ws + WS_NBR_OFF);
    float* part          = (float*)((char*)d_ws + WS_PART_OFF);

    const float4* rawv = (const float4*)raw;
    const float4* latv = (const float4*)latent;

    hipMemsetAsync(d_ws, 0, 256, stream);  // zero accum
    prep_kernel<<<B_N / 256, 256, 0, stream>>>(rawv, latv, (const float4*)outputs,
                                               (const float4*)targets, sq, rawh, rawl,
                                               lath, latl, accum);
    thresh_kernel<<<B_N / 16, 256, 0, stream>>>(rawv, rawh, sq, T);
    scan_kernel<<<B_N / 32, 1024, 0, stream>>>(rawh, rawl, sq, T, nbrG);
    eig_kernel<<<B_N / 4, 256, 0, stream>>>(lath, latl, rawh, rawl, nbrG, part);
    final_kernel<<<1, 256, 0, stream>>>(accum, part, (float*)d_out);
}

// Round 16
// 245.316 us; speedup vs baseline: 1.0246x; 1.0246x over previous
//
#include <hip/hip_runtime.h>
#include <cstdint>
#include <cstddef>

// Problem constants
#define B_N   16384
#define D_DIM 16
#define K_NBR 25
#define CAP   256       // per-row LDS candidate capacity (E[C]~96)
#define MAXL  4         // CAP/64
#define NSAMP 1024      // threshold sample count per row
#define EPAD  20        // u16 row pad for eig staging buffers
#define NPART (B_N / 4) // per-block partials from eig (4096)

// Workspace: accum | sq | T | rawh | rawl | lath | latl | nbrG | part
#define WS_SQ_OFF   256
#define WS_T_OFF    (WS_SQ_OFF + 65536)
#define WS_RAWH_OFF (WS_T_OFF + 65536)
#define WS_RAWL_OFF (WS_RAWH_OFF + B_N * D_DIM * 2)
#define WS_LATH_OFF (WS_RAWL_OFF + B_N * D_DIM * 2)
#define WS_LATL_OFF (WS_LATH_OFF + B_N * D_DIM * 2)
#define WS_NBR_OFF  (WS_LATL_OFF + B_N * D_DIM * 2)
#define WS_PART_OFF (WS_NBR_OFF + B_N * K_NBR * 4)

typedef __attribute__((ext_vector_type(8))) short bf16x8;
typedef __attribute__((ext_vector_type(4))) float f32x4;

__device__ __forceinline__ unsigned map_f32(float x) {
    unsigned u = __float_as_uint(x);
    return (u & 0x80000000u) ? ~u : (u | 0x80000000u); // order-preserving
}

__device__ __forceinline__ unsigned short f2bf(float x) {   // RNE f32->bf16 bits
    unsigned u = __float_as_uint(x);
    unsigned r = (u + 0x7FFFu + ((u >> 16) & 1u)) >> 16;
    return (unsigned short)r;
}
__device__ __forceinline__ float bf2f(unsigned short h) {
    return __uint_as_float(((unsigned)h) << 16);
}

// ---------------------------------------------------------------- prep: sq + recon + bf16 hi/lo splits
__global__ __launch_bounds__(256) void prep_kernel(const float4* __restrict__ rawv,
                                                   const float4* __restrict__ latv,
                                                   const float4* __restrict__ ov,
                                                   const float4* __restrict__ tv,
                                                   float* __restrict__ sq,
                                                   unsigned short* __restrict__ rawh,
                                                   unsigned short* __restrict__ rawl,
                                                   unsigned short* __restrict__ lath,
                                                   unsigned short* __restrict__ latl,
                                                   float* __restrict__ accum) {
    int i = blockIdx.x * 256 + threadIdx.x;
    float v[16];
    {
        float4 r0 = rawv[i*4+0], r1 = rawv[i*4+1], r2 = rawv[i*4+2], r3 = rawv[i*4+3];
        v[0]=r0.x; v[1]=r0.y; v[2]=r0.z; v[3]=r0.w;
        v[4]=r1.x; v[5]=r1.y; v[6]=r1.z; v[7]=r1.w;
        v[8]=r2.x; v[9]=r2.y; v[10]=r2.z; v[11]=r2.w;
        v[12]=r3.x; v[13]=r3.y; v[14]=r3.z; v[15]=r3.w;
    }
    float s = 0.0f;
    unsigned short h[16], l[16];
    #pragma unroll
    for (int k = 0; k < 16; ++k) {
        s = fmaf(v[k], v[k], s);
        unsigned short hh = f2bf(v[k]);
        h[k] = hh;
        l[k] = f2bf(v[k] - bf2f(hh));
    }
    sq[i] = s;
    #pragma unroll
    for (int q = 0; q < 4; ++q) {
        ((ushort4*)(rawh + (size_t)i*16))[q] = make_ushort4(h[q*4], h[q*4+1], h[q*4+2], h[q*4+3]);
        ((ushort4*)(rawl + (size_t)i*16))[q] = make_ushort4(l[q*4], l[q*4+1], l[q*4+2], l[q*4+3]);
    }
    // latent split
    {
        float4 r0 = latv[i*4+0], r1 = latv[i*4+1], r2 = latv[i*4+2], r3 = latv[i*4+3];
        v[0]=r0.x; v[1]=r0.y; v[2]=r0.z; v[3]=r0.w;
        v[4]=r1.x; v[5]=r1.y; v[6]=r1.z; v[7]=r1.w;
        v[8]=r2.x; v[9]=r2.y; v[10]=r2.z; v[11]=r2.w;
        v[12]=r3.x; v[13]=r3.y; v[14]=r3.z; v[15]=r3.w;
        #pragma unroll
        for (int k = 0; k < 16; ++k) {
            unsigned short hh = f2bf(v[k]);
            h[k] = hh;
            l[k] = f2bf(v[k] - bf2f(hh));
        }
        #pragma unroll
        for (int q = 0; q < 4; ++q) {
            ((ushort4*)(lath + (size_t)i*16))[q] = make_ushort4(h[q*4], h[q*4+1], h[q*4+2], h[q*4+3]);
            ((ushort4*)(latl + (size_t)i*16))[q] = make_ushort4(l[q*4], l[q*4+1], l[q*4+2], l[q*4+3]);
        }
    }

    float rs = 0.0f;
    #pragma unroll
    for (int q = 0; q < 4; ++q) {
        float4 o = ov[i*4+q], t = tv[i*4+q];
        float d;
        d = o.x - t.x; rs = fmaf(d, d, rs);
        d = o.y - t.y; rs = fmaf(d, d, rs);
        d = o.z - t.z; rs = fmaf(d, d, rs);
        d = o.w - t.w; rs = fmaf(d, d, rs);
    }
    #pragma unroll
    for (int off = 32; off >= 1; off >>= 1) rs += __shfl_down(rs, off, 64);
    if ((threadIdx.x & 63) == 0) atomicAdd(&accum[0], rs);   // 256 atomics total: negligible
}

// ---------------------------------------------------------------- per-row distance threshold, LDS-staged
__global__ __launch_bounds__(256) void thresh_kernel(const float4* __restrict__ rawv,
                                                     const unsigned short* __restrict__ rawh,
                                                     const float* __restrict__ sq,
                                                     float* __restrict__ T) {
    __shared__ unsigned short sampH[NSAMP * 16];
    __shared__ float sampSq[NSAMP];
    __shared__ float V[16][48];

    int tid = threadIdx.x;
    for (int s = tid; s < NSAMP; s += 256) {
        int js = s << 4;
        const uint4* src = (const uint4*)(rawh + (size_t)js * 16);
        ((uint4*)(sampH + s * 16))[0] = src[0];
        ((uint4*)(sampH + s * 16))[1] = src[1];
        sampSq[s] = sq[js];
    }

    int rl   = tid >> 4;
    int sidx = tid & 15;
    int i = blockIdx.x * 16 + rl;

    float a[16];
    {
        float4 r0 = rawv[i*4+0], r1 = rawv[i*4+1], r2 = rawv[i*4+2], r3 = rawv[i*4+3];
        a[0]=r0.x; a[1]=r0.y; a[2]=r0.z; a[3]=r0.w;
        a[4]=r1.x; a[5]=r1.y; a[6]=r1.z; a[7]=r1.w;
        a[8]=r2.x; a[9]=r2.y; a[10]=r2.z; a[11]=r2.w;
        a[12]=r3.x; a[13]=r3.y; a[14]=r3.z; a[15]=r3.w;
    }
    float sqi = sq[i];
    __syncthreads();

    float s0 = 3e37f, s1 = 3e37f, s2 = 3e37f;
    for (int t = 0; t < NSAMP / 16; ++t) {
        int s = t * 16 + sidx;
        const uint4* bp = (const uint4*)(sampH + s * 16);
        uint4 h0 = bp[0], h1 = bp[1];
        float dot = 0.0f;
        unsigned w;
        w = h0.x; dot = fmaf(a[0],  __uint_as_float(w << 16), dot); dot = fmaf(a[1],  __uint_as_float(w & 0xFFFF0000u), dot);
        w = h0.y; dot = fmaf(a[2],  __uint_as_float(w << 16), dot); dot = fmaf(a[3],  __uint_as_float(w & 0xFFFF0000u), dot);
        w = h0.z; dot = fmaf(a[4],  __uint_as_float(w << 16), dot); dot = fmaf(a[5],  __uint_as_float(w & 0xFFFF0000u), dot);
        w = h0.w; dot = fmaf(a[6],  __uint_as_float(w << 16), dot); dot = fmaf(a[7],  __uint_as_float(w & 0xFFFF0000u), dot);
        w = h1.x; dot = fmaf(a[8],  __uint_as_float(w << 16), dot); dot = fmaf(a[9],  __uint_as_float(w & 0xFFFF0000u), dot);
        w = h1.y; dot = fmaf(a[10], __uint_as_float(w << 16), dot); dot = fmaf(a[11], __uint_as_float(w & 0xFFFF0000u), dot);
        w = h1.z; dot = fmaf(a[12], __uint_as_float(w << 16), dot); dot = fmaf(a[13], __uint_as_float(w & 0xFFFF0000u), dot);
        w = h1.w; dot = fmaf(a[14], __uint_as_float(w << 16), dot); dot = fmaf(a[15], __uint_as_float(w & 0xFFFF0000u), dot);
        float cur = sqi + sampSq[s] - 2.0f * dot;
        float lo;
        lo = fminf(s0, cur); cur = fmaxf(s0, cur); s0 = lo;
        lo = fminf(s1, cur); cur = fmaxf(s1, cur); s1 = lo;
        lo = fminf(s2, cur); cur = fmaxf(s2, cur); s2 = lo;
    }

    V[rl][sidx*3+0] = s0; V[rl][sidx*3+1] = s1; V[rl][sidx*3+2] = s2;
    __syncthreads();

    int cl0 = 0, cq0 = 0, cl1 = 0, cq1 = 0, cl2 = 0, cq2 = 0;
    for (int k = 0; k < 48; ++k) {
        float v = V[rl][k];
        cl0 += (v < s0); cq0 += (v <= s0);
        cl1 += (v < s1); cq1 += (v <= s1);
        cl2 += (v < s2); cq2 += (v <= s2);
    }
    if (cl0 <= 5 && 5 < cq0) T[i] = s0 + 0.05f;
    else if (cl1 <= 5 && 5 < cq1) T[i] = s1 + 0.05f;
    else if (cl2 <= 5 && 5 < cq2) T[i] = s2 + 0.05f;
}

// Epilogue for one tile: 2 mat-halves x 4 r; hs = 0.5*sqj hoisted.
#define SCAN_EPI(A0, A1, SQJ, JJ)                                                         \
    {                                                                                     \
        float hs_ = 0.5f * (SQJ);                                                         \
        _Pragma("unroll")                                                                 \
        for (int r = 0; r < 4; ++r) {                                                     \
            int m0_ = quad * 4 + r, m1_ = m0_ + 16;                                       \
            if (((A0)[r] > hs_ + hcut[r]) && ((JJ) != i0 + m0_)) {                        \
                float d2_ = sqi[r] + (SQJ) - 2.0f * (A0)[r];                              \
                int pos_ = atomicAdd(&cntS[m0_], 1);                                      \
                if (pos_ < CAP) keyS[m0_ * CAP + pos_] =                                  \
                    (map_f32(d2_) & 0xFFFF0000u) | (unsigned)(JJ);                        \
            }                                                                             \
            if (((A1)[r] > hs_ + hcut[4+r]) && ((JJ) != i0 + m1_)) {                      \
                float d2_ = sqi[4+r] + (SQJ) - 2.0f * (A1)[r];                            \
                int pos_ = atomicAdd(&cntS[m1_], 1);                                      \
                if (pos_ < CAP) keyS[m1_ * CAP + pos_] =                                  \
                    (map_f32(d2_) & 0xFFFF0000u) | (unsigned)(JJ);                        \
            }                                                                             \
        }                                                                                 \
    }

// ---------------------------------------------------------------- MFMA scan + select: 32 rows/block,
// 1024 thr, 4-tile ILP. R15 post-mortem: adding waves didn't lift VALUBusy (47%) -> stall is the
// per-wave serial load->MFMA->epilogue chain; 4 independent tile chains halve exposed L2 latency.
// NOTE: plain __launch_bounds__ only — a second argument caused a 64-VGPR cap + unified-AGPR
// split and massive scratch spill on gfx950 (R7/R8). Do not add it.
__global__ __launch_bounds__(1024) void scan_kernel(const unsigned short* __restrict__ rawh,
                                                    const unsigned short* __restrict__ rawl,
                                                    const float* __restrict__ sq,
                                                    const float* __restrict__ T,
                                                    unsigned* __restrict__ nbrG) {
    __shared__ unsigned keyS[32 * CAP];
    __shared__ int      cntS[32];
    __shared__ int      nbrW[32][K_NBR];

    int tid  = threadIdx.x;
    int wave = tid >> 6;       // 0..15
    int lane = tid & 63;
    int quad = lane >> 4;
    int lnib = lane & 15;
    int i0   = blockIdx.x * 32;
    int koff = (quad & 1) * 8;

    if (tid < 32) cntS[tid] = 0;

    const unsigned short* ab = (quad < 2 ? rawh : rawl) + (size_t)(i0 + lnib) * 16 + koff;
    bf16x8 afrag0 = *(const bf16x8*)ab;
    bf16x8 afrag1 = *(const bf16x8*)(ab + 16 * 16);

    float sqi[8], hcut[8];
    #pragma unroll
    for (int r = 0; r < 4; ++r) {
        int m = quad * 4 + r;
        sqi[r]     = sq[i0 + m];
        hcut[r]    = 0.5f * (sqi[r] - T[i0 + m]);
        sqi[4+r]   = sq[i0 + m + 16];
        hcut[4+r]  = 0.5f * (sqi[4+r] - T[i0 + m + 16]);
    }
    __syncthreads();

    // ---- phase 1: 1024 j-tiles over 16 waves, 4-tile ILP (t, t+16, t+32, t+48; stride 64)
    for (int t = wave; t < B_N / 16; t += 64) {
        int jA = t * 16 + lnib;
        int jB = jA + 256;
        int jC = jA + 512;
        int jD = jA + 768;
        bf16x8 bhA = *(const bf16x8*)(rawh + (size_t)jA * 16 + koff);
        bf16x8 blA = *(const bf16x8*)(rawl + (size_t)jA * 16 + koff);
        bf16x8 bhB = *(const bf16x8*)(rawh + (size_t)jB * 16 + koff);
        bf16x8 blB = *(const bf16x8*)(rawl + (size_t)jB * 16 + koff);
        bf16x8 bhC = *(const bf16x8*)(rawh + (size_t)jC * 16 + koff);
        bf16x8 blC = *(const bf16x8*)(rawl + (size_t)jC * 16 + koff);
        bf16x8 bhD = *(const bf16x8*)(rawh + (size_t)jD * 16 + koff);
        bf16x8 blD = *(const bf16x8*)(rawl + (size_t)jD * 16 + koff);
        float sqjA = sq[jA];
        float sqjB = sq[jB];
        float sqjC = sq[jC];
        float sqjD = sq[jD];
        f32x4 a0A = {0,0,0,0}, a1A = {0,0,0,0}, a0B = {0,0,0,0}, a1B = {0,0,0,0};
        f32x4 a0C = {0,0,0,0}, a1C = {0,0,0,0}, a0D = {0,0,0,0}, a1D = {0,0,0,0};
        a0A = __builtin_amdgcn_mfma_f32_16x16x32_bf16(afrag0, blA, a0A, 0, 0, 0);
        a1A = __builtin_amdgcn_mfma_f32_16x16x32_bf16(afrag1, blA, a1A, 0, 0, 0);
        a0B = __builtin_amdgcn_mfma_f32_16x16x32_bf16(afrag0, blB, a0B, 0, 0, 0);
        a1B = __builtin_amdgcn_mfma_f32_16x16x32_bf16(afrag1, blB, a1B, 0, 0, 0);
        a0C = __builtin_amdgcn_mfma_f32_16x16x32_bf16(afrag0, blC, a0C, 0, 0, 0);
        a1C = __builtin_amdgcn_mfma_f32_16x16x32_bf16(afrag1, blC, a1C, 0, 0, 0);
        a0D = __builtin_amdgcn_mfma_f32_16x16x32_bf16(afrag0, blD, a0D, 0, 0, 0);
        a1D = __builtin_amdgcn_mfma_f32_16x16x32_bf16(afrag1, blD, a1D, 0, 0, 0);
        a0A = __builtin_amdgcn_mfma_f32_16x16x32_bf16(afrag0, bhA, a0A, 0, 0, 0);
        a1A = __builtin_amdgcn_mfma_f32_16x16x32_bf16(afrag1, bhA, a1A, 0, 0, 0);
        a0B = __builtin_amdgcn_mfma_f32_16x16x32_bf16(afrag0, bhB, a0B, 0, 0, 0);
        a1B = __builtin_amdgcn_mfma_f32_16x16x32_bf16(afrag1, bhB, a1B, 0, 0, 0);
        a0C = __builtin_amdgcn_mfma_f32_16x16x32_bf16(afrag0, bhC, a0C, 0, 0, 0);
        a1C = __builtin_amdgcn_mfma_f32_16x16x32_bf16(afrag1, bhC, a1C, 0, 0, 0);
        a0D = __builtin_amdgcn_mfma_f32_16x16x32_bf16(afrag0, bhD, a0D, 0, 0, 0);
        a1D = __builtin_amdgcn_mfma_f32_16x16x32_bf16(afrag1, bhD, a1D, 0, 0, 0);
        SCAN_EPI(a0A, a1A, sqjA, jA)
        SCAN_EPI(a0B, a1B, sqjB, jB)
        SCAN_EPI(a0C, a1C, sqjC, jC)
        SCAN_EPI(a0D, a1D, sqjD, jD)
    }
    __syncthreads();

    // ---- phase 2: 16 waves x 2 rows: bisection select + ballot-prefix collect
    unsigned long long ltm = (1ull << lane) - 1ull;
    for (int rr = 0; rr < 2; ++rr) {
        int m  = wave * 2 + rr;
        int pt = i0 + m;
        int C = cntS[m]; C = C < CAP ? C : CAP;
        unsigned kl[MAXL];
        #pragma unroll
        for (int tt = 0; tt < MAXL; ++tt) {
            int c = tt * 64 + lane;
            kl[tt] = (c < C) ? keyS[m * CAP + c] : 0xFFFFFFFFu;
        }
        unsigned lo = 0, hi = 0xFFFFFFFEu;
        for (int it = 0; it < 32 && lo < hi; ++it) {
            unsigned mid = lo + ((hi - lo) >> 1);
            unsigned cc = 0;
            #pragma unroll
            for (int tt = 0; tt < MAXL; ++tt)
                cc += (unsigned)__builtin_popcountll(__ballot(kl[tt] <= mid));
            if (cc >= K_NBR) hi = mid; else lo = mid + 1;
        }
        unsigned T25 = hi;

        int base = 0;
        #pragma unroll
        for (int tt = 0; tt < MAXL; ++tt) {
            bool c = kl[tt] <= T25;
            unsigned long long mk = __ballot(c);
            if (c) {
                int pos = base + __builtin_popcountll(mk & ltm);
                if (pos < K_NBR) nbrW[m][pos] = (int)(kl[tt] & 0xFFFFu);
            }
            base += __builtin_popcountll(mk);
        }
        if (lane == 0) {
            int got = base < K_NBR ? base : K_NBR;
            int pad = (got > 0) ? nbrW[m][0] : pt;
            for (int q = got; q < K_NBR; ++q) nbrW[m][q] = pad;
        }
        if (lane < K_NBR) nbrG[(size_t)pt * K_NBR + lane] = (unsigned)nbrW[m][lane];
    }
}

// ---------------------------------------------------------------- eig v7: MFMA trace, 5 squarings (C^32)
__global__ __launch_bounds__(256) void eig_kernel(const unsigned short* __restrict__ lath,
                                                  const unsigned short* __restrict__ latl,
                                                  const unsigned short* __restrict__ rawh,
                                                  const unsigned short* __restrict__ rawl,
                                                  const unsigned* __restrict__ nbrG,
                                                  float* __restrict__ part) {
    __shared__ unsigned short MS[4][2][2][32 * EPAD];  // [wave][comm][h/l]; rows 25..31 zeroed
    __shared__ unsigned short CH[4][2][32 * EPAD];     // [wave][comm]; rows 0..15 hi, 16..31 lo
    __shared__ float psum[4];

    int wave = threadIdx.x >> 6;
    int lane = threadIdx.x & 63;
    int quad = lane >> 4;
    int lnib = lane & 15;
    int pt   = blockIdx.x * 4 + wave;

    {
        int comm = lane >> 5;
        int row  = lane & 31;
        uint2* dh = (uint2*)&MS[wave][comm][0][row * EPAD];
        uint2* dl = (uint2*)&MS[wave][comm][1][row * EPAD];
        if (row < K_NBR) {
            int n = (int)nbrG[(size_t)pt * K_NBR + row];
            const uint2* sh = (const uint2*)((comm ? rawh : lath) + (size_t)n * 16);
            const uint2* sl = (const uint2*)((comm ? rawl : latl) + (size_t)n * 16);
            dh[0] = sh[0]; dh[1] = sh[1]; dh[2] = sh[2]; dh[3] = sh[3];
            dl[0] = sl[0]; dl[1] = sl[1]; dl[2] = sl[2]; dl[3] = sl[3];
        } else {
            uint2 z = make_uint2(0u, 0u);
            dh[0] = z; dh[1] = z; dh[2] = z; dh[3] = z;
            dl[0] = z; dl[1] = z; dl[2] = z; dl[3] = z;
        }
    }
    __syncthreads();

    bf16x8 ones;
    #pragma unroll
    for (int j = 0; j < 8; ++j) ones[j] = (short)0x3F80;

    const unsigned short* Mzh = &MS[wave][0][0][0];
    const unsigned short* Mzl = &MS[wave][0][1][0];
    const unsigned short* Mxh = &MS[wave][1][0][0];
    const unsigned short* Mxl = &MS[wave][1][1][0];

    bf16x8 fzh, fzl, fxh, fxl;
    #pragma unroll
    for (int j = 0; j < 8; ++j) {
        int k = quad * 8 + j;
        fzh[j] = (short)Mzh[k * EPAD + lnib];
        fzl[j] = (short)Mzl[k * EPAD + lnib];
        fxh[j] = (short)Mxh[k * EPAD + lnib];
        fxl[j] = (short)Mxl[k * EPAD + lnib];
    }

    f32x4 mz = {0.f,0.f,0.f,0.f}, mx = {0.f,0.f,0.f,0.f};
    mz = __builtin_amdgcn_mfma_f32_16x16x32_bf16(fzh, fzh, mz, 0, 0, 0);
    mx = __builtin_amdgcn_mfma_f32_16x16x32_bf16(fxh, fxh, mx, 0, 0, 0);
    mz = __builtin_amdgcn_mfma_f32_16x16x32_bf16(fzh, fzl, mz, 0, 0, 0);
    mx = __builtin_amdgcn_mfma_f32_16x16x32_bf16(fxh, fxl, mx, 0, 0, 0);
    mz = __builtin_amdgcn_mfma_f32_16x16x32_bf16(fzl, fzh, mz, 0, 0, 0);
    mx = __builtin_amdgcn_mfma_f32_16x16x32_bf16(fxl, fxh, mx, 0, 0, 0);
    f32x4 dz1 = {0.f,0.f,0.f,0.f}, dx1 = {0.f,0.f,0.f,0.f};
    dz1 = __builtin_amdgcn_mfma_f32_16x16x32_bf16(fzh, ones, dz1, 0, 0, 0);
    dx1 = __builtin_amdgcn_mfma_f32_16x16x32_bf16(fxh, ones, dx1, 0, 0, 0);
    dz1 = __builtin_amdgcn_mfma_f32_16x16x32_bf16(fzl, ones, dz1, 0, 0, 0);
    dx1 = __builtin_amdgcn_mfma_f32_16x16x32_bf16(fxl, ones, dx1, 0, 0, 0);
    f32x4 dz2 = {0.f,0.f,0.f,0.f}, dx2 = {0.f,0.f,0.f,0.f};
    dz2 = __builtin_amdgcn_mfma_f32_16x16x32_bf16(ones, fzh, dz2, 0, 0, 0);
    dx2 = __builtin_amdgcn_mfma_f32_16x16x32_bf16(ones, fxh, dx2, 0, 0, 0);
    dz2 = __builtin_amdgcn_mfma_f32_16x16x32_bf16(ones, fzl, dz2, 0, 0, 0);
    dx2 = __builtin_amdgcn_mfma_f32_16x16x32_bf16(ones, fxl, dx2, 0, 0, 0);

    f32x4 az, ax;
    #pragma unroll
    for (int r = 0; r < 4; ++r) {
        az[r] = mz[r] - dz1[r] * dz2[r] * 0.04f;
        ax[r] = mx[r] - dx1[r] * dx2[r] * 0.04f;
    }

    bool dg = (quad == (lnib >> 2));

    {
        float tz = dg ? az[lnib & 3] : 0.0f;
        float tx = dg ? ax[lnib & 3] : 0.0f;
        #pragma unroll
        for (int off = 1; off < 64; off <<= 1) {
            tz += __shfl_xor(tz, off, 64);
            tx += __shfl_xor(tx, off, 64);
        }
        float iz = 1.0f / fmaxf(tz, 1e-30f), ix = 1.0f / fmaxf(tx, 1e-30f);
        #pragma unroll
        for (int r = 0; r < 4; ++r) { az[r] *= iz; ax[r] *= ix; }
    }

    unsigned short* Bz = &CH[wave][0][0];
    unsigned short* Bx = &CH[wave][1][0];
    for (int s = 0; s < 5; ++s) {     // C^32 (R13: C^64 gave absmax 0.0 with margin)
        #pragma unroll
        for (int r = 0; r < 4; ++r) {
            int row = quad * 4 + r;
            unsigned short zh = f2bf(az[r]);
            unsigned short xh = f2bf(ax[r]);
            Bz[row * EPAD + lnib]        = zh;
            Bx[row * EPAD + lnib]        = xh;
            Bz[(row + 16) * EPAD + lnib] = f2bf(az[r] - bf2f(zh));
            Bx[(row + 16) * EPAD + lnib] = f2bf(ax[r] - bf2f(xh));
        }
        bf16x8 fz, gz, fx, gx;
        #pragma unroll
        for (int j = 0; j < 8; ++j) {
            int k  = quad * 8 + j;
            int ks = (k + 16) & 31;
            fz[j] = (short)Bz[k  * EPAD + lnib];
            gz[j] = (short)Bz[ks * EPAD + lnib];
            fx[j] = (short)Bx[k  * EPAD + lnib];
            gx[j] = (short)Bx[ks * EPAD + lnib];
        }
        f32x4 nz = {0.f,0.f,0.f,0.f}, nx = {0.f,0.f,0.f,0.f};
        nz = __builtin_amdgcn_mfma_f32_16x16x32_bf16(fz, fz, nz, 0, 0, 0);
        nx = __builtin_amdgcn_mfma_f32_16x16x32_bf16(fx, fx, nx, 0, 0, 0);
        nz = __builtin_amdgcn_mfma_f32_16x16x32_bf16(fz, gz, nz, 0, 0, 0);
        nx = __builtin_amdgcn_mfma_f32_16x16x32_bf16(fx, gx, nx, 0, 0, 0);
        if (s == 2) {
            float tz = dg ? nz[lnib & 3] : 0.0f;
            float tx = dg ? nx[lnib & 3] : 0.0f;
            #pragma unroll
            for (int off = 1; off < 64; off <<= 1) {
                tz += __shfl_xor(tz, off, 64);
                tx += __shfl_xor(tx, off, 64);
            }
            float iz = 1.0f / fmaxf(tz, 1e-30f), ix = 1.0f / fmaxf(tx, 1e-30f);
            #pragma unroll
            for (int r = 0; r < 4; ++r) { az[r] = nz[r] * iz; ax[r] = nx[r] * ix; }
        } else {
            #pragma unroll
            for (int r = 0; r < 4; ++r) { az[r] = nz[r]; ax[r] = nx[r]; }
        }
    }

    float tz = dg ? az[lnib & 3] : 0.0f;
    float tx = dg ? ax[lnib & 3] : 0.0f;
    float dt = az[0]*ax[0] + az[1]*ax[1] + az[2]*ax[2] + az[3]*ax[3];
    #pragma unroll
    for (int off = 1; off < 64; off <<= 1) {
        tz += __shfl_xor(tz, off, 64);
        tx += __shfl_xor(tx, off, 64);
        dt += __shfl_xor(dt, off, 64);
    }
    if (lane == 0) psum[wave] = dt / fmaxf(tz * tx, 1e-30f);
    __syncthreads();
    if (threadIdx.x == 0)
        part[blockIdx.x] = psum[0] + psum[1] + psum[2] + psum[3];   // plain store, no atomic
}

// ---------------------------------------------------------------- final: reduce partials + combine
__global__ __launch_bounds__(256) void final_kernel(const float* __restrict__ accum,
                                                    const float* __restrict__ part,
                                                    float* __restrict__ out) {
    __shared__ float ws[4];
    int tid = threadIdx.x;
    float s = 0.0f;
    for (int i = tid; i < NPART; i += 256) s += part[i];
    #pragma unroll
    for (int off = 32; off >= 1; off >>= 1) s += __shfl_down(s, off, 64);
    if ((tid & 63) == 0) ws[tid >> 6] = s;
    __syncthreads();
    if (tid == 0) {
        float dot2  = ws[0] + ws[1] + ws[2] + ws[3];
        float recon = accum[0] * (1.0f / (float)(B_N * D_DIM));
        float tsa   = 2.0f - 2.0f * (dot2 * (1.0f / (float)B_N));
        out[0] = recon + 0.1f * tsa;
    }
}

extern "C" void kernel_launch(void* const* d_in, const int* in_sizes, int n_in,
                              void* d_out, int out_size, void* d_ws, size_t ws_size,
                              hipStream_t stream) {
    const float* outputs = (const float*)d_in[0];
    const float* targets = (const float*)d_in[1];
    const float* latent  = (const float*)d_in[2];
    const float* raw     = (const float*)d_in[3];

    float* accum         = (float*)d_ws;
    float* sq            = (float*)((char*)d_ws + WS_SQ_OFF);
    float* T             = (float*)((char*)d_ws + WS_T_OFF);
    unsigned short* rawh = (unsigned short*)((char*)d_ws + WS_RAWH_OFF);
    unsigned short* rawl = (unsigned short*)((char*)d_ws + WS_RAWL_OFF);
    unsigned short* lath = (unsigned short*)((char*)d_ws + WS_LATH_OFF);
    unsigned short* latl = (unsigned short*)((char*)d_ws + WS_LATL_OFF);
    unsigned* nbrG       = (unsigned*)((char*)d_ws + WS_NBR_OFF);
    float* part          = (float*)((char*)d_ws + WS_PART_OFF);

    const float4* rawv = (const float4*)raw;
    const float4* latv = (const float4*)latent;

    hipMemsetAsync(d_ws, 0, 256, stream);  // zero accum
    prep_kernel<<<B_N / 256, 256, 0, stream>>>(rawv, latv, (const float4*)outputs,
                                               (const float4*)targets, sq, rawh, rawl,
                                               lath, latl, accum);
    thresh_kernel<<<B_N / 16, 256, 0, stream>>>(rawv, rawh, sq, T);
    scan_kernel<<<B_N / 32, 1024, 0, stream>>>(rawh, rawl, sq, T, nbrG);
    eig_kernel<<<B_N / 4, 256, 0, stream>>>(lath, latl, rawh, rawl, nbrG, part);
    final_kernel<<<1, 256, 0, stream>>>(accum, part, (float*)d_out);
}

// Round 17
// 208.500 us; speedup vs baseline: 1.2055x; 1.1766x over previous
//
#include <hip/hip_runtime.h>
#include <cstdint>
#include <cstddef>

// Problem constants
#define B_N   16384
#define D_DIM 16
#define K_NBR 25
#define SCAP  512       // keys per row in selection (256 slices x 2)
#define SMAXL 8         // SCAP/64
#define EPAD  20        // u16 row pad for eig staging buffers
#define NPART (B_N / 4) // per-block partials from eig (4096)

// Workspace: accum | sq | rawh | rawl | lath | latl | nbrG | part
#define WS_SQ_OFF   256
#define WS_RAWH_OFF (WS_SQ_OFF + 65536)
#define WS_RAWL_OFF (WS_RAWH_OFF + B_N * D_DIM * 2)
#define WS_LATH_OFF (WS_RAWL_OFF + B_N * D_DIM * 2)
#define WS_LATL_OFF (WS_LATH_OFF + B_N * D_DIM * 2)
#define WS_NBR_OFF  (WS_LATL_OFF + B_N * D_DIM * 2)
#define WS_PART_OFF (WS_NBR_OFF + B_N * K_NBR * 4)

typedef __attribute__((ext_vector_type(8))) short bf16x8;
typedef __attribute__((ext_vector_type(4))) float f32x4;

__device__ __forceinline__ unsigned short f2bf(float x) {   // RNE f32->bf16 bits
    unsigned u = __float_as_uint(x);
    unsigned r = (u + 0x7FFFu + ((u >> 16) & 1u)) >> 16;
    return (unsigned short)r;
}
__device__ __forceinline__ float bf2f(unsigned short h) {
    return __uint_as_float(((unsigned)h) << 16);
}

// ---------------------------------------------------------------- prep: sq + recon + bf16 hi/lo splits
__global__ __launch_bounds__(256) void prep_kernel(const float4* __restrict__ rawv,
                                                   const float4* __restrict__ latv,
                                                   const float4* __restrict__ ov,
                                                   const float4* __restrict__ tv,
                                                   float* __restrict__ sq,
                                                   unsigned short* __restrict__ rawh,
                                                   unsigned short* __restrict__ rawl,
                                                   unsigned short* __restrict__ lath,
                                                   unsigned short* __restrict__ latl,
                                                   float* __restrict__ accum) {
    int i = blockIdx.x * 256 + threadIdx.x;
    float v[16];
    {
        float4 r0 = rawv[i*4+0], r1 = rawv[i*4+1], r2 = rawv[i*4+2], r3 = rawv[i*4+3];
        v[0]=r0.x; v[1]=r0.y; v[2]=r0.z; v[3]=r0.w;
        v[4]=r1.x; v[5]=r1.y; v[6]=r1.z; v[7]=r1.w;
        v[8]=r2.x; v[9]=r2.y; v[10]=r2.z; v[11]=r2.w;
        v[12]=r3.x; v[13]=r3.y; v[14]=r3.z; v[15]=r3.w;
    }
    float s = 0.0f;
    unsigned short h[16], l[16];
    #pragma unroll
    for (int k = 0; k < 16; ++k) {
        s = fmaf(v[k], v[k], s);
        unsigned short hh = f2bf(v[k]);
        h[k] = hh;
        l[k] = f2bf(v[k] - bf2f(hh));
    }
    sq[i] = s;
    #pragma unroll
    for (int q = 0; q < 4; ++q) {
        ((ushort4*)(rawh + (size_t)i*16))[q] = make_ushort4(h[q*4], h[q*4+1], h[q*4+2], h[q*4+3]);
        ((ushort4*)(rawl + (size_t)i*16))[q] = make_ushort4(l[q*4], l[q*4+1], l[q*4+2], l[q*4+3]);
    }
    // latent split
    {
        float4 r0 = latv[i*4+0], r1 = latv[i*4+1], r2 = latv[i*4+2], r3 = latv[i*4+3];
        v[0]=r0.x; v[1]=r0.y; v[2]=r0.z; v[3]=r0.w;
        v[4]=r1.x; v[5]=r1.y; v[6]=r1.z; v[7]=r1.w;
        v[8]=r2.x; v[9]=r2.y; v[10]=r2.z; v[11]=r2.w;
        v[12]=r3.x; v[13]=r3.y; v[14]=r3.z; v[15]=r3.w;
        #pragma unroll
        for (int k = 0; k < 16; ++k) {
            unsigned short hh = f2bf(v[k]);
            h[k] = hh;
            l[k] = f2bf(v[k] - bf2f(hh));
        }
        #pragma unroll
        for (int q = 0; q < 4; ++q) {
            ((ushort4*)(lath + (size_t)i*16))[q] = make_ushort4(h[q*4], h[q*4+1], h[q*4+2], h[q*4+3]);
            ((ushort4*)(latl + (size_t)i*16))[q] = make_ushort4(l[q*4], l[q*4+1], l[q*4+2], l[q*4+3]);
        }
    }

    float rs = 0.0f;
    #pragma unroll
    for (int q = 0; q < 4; ++q) {
        float4 o = ov[i*4+q], t = tv[i*4+q];
        float d;
        d = o.x - t.x; rs = fmaf(d, d, rs);
        d = o.y - t.y; rs = fmaf(d, d, rs);
        d = o.z - t.z; rs = fmaf(d, d, rs);
        d = o.w - t.w; rs = fmaf(d, d, rs);
    }
    #pragma unroll
    for (int off = 32; off >= 1; off >>= 1) rs += __shfl_down(rs, off, 64);
    if ((threadIdx.x & 63) == 0) atomicAdd(&accum[0], rs);   // 256 atomics total: negligible
}

// ---------------------------------------------------------------- MFMA scan + branchless per-slice top-2
// R16 post-mortem: the branchy filter epilogue (LDS ds_add_rtn in sequential branch bodies, ~70 cyc
// each, non-overlapping) was the 50% stall — not load latency (TLP R15 and ILP R16 both no-ops).
// v2: each (wave,lnib) slice keeps the 2 smallest keys per row in REGISTERS, branchless
// (fma+add+and_or+3 min/max per value); no threshold kernel, no atomics, no branches.
// Key = (d2_bits & 0x7FFFC000) | 0x80000000 | j : 14-bit j, 9 mantissa bits (4x finer than the
// old 16-bit key). Selection: 512 keys/row -> wave bisection for the 26 smallest (self skipped
// by j-compare). Two 16-row groups reuse one 32 KB LDS buffer.
// NOTE: plain __launch_bounds__ only — a second argument caused a 64-VGPR cap + unified-AGPR
// split and massive scratch spill on gfx950 (R7/R8). Do not add it.
__global__ __launch_bounds__(1024) void scan_kernel(const unsigned short* __restrict__ rawh,
                                                    const unsigned short* __restrict__ rawl,
                                                    const float* __restrict__ sq,
                                                    unsigned* __restrict__ nbrG) {
    __shared__ unsigned keyS[16 * SCAP];   // 32 KB, one 16-row group at a time
    __shared__ int      nbrW[16][K_NBR];

    int tid  = threadIdx.x;
    int wave = tid >> 6;       // 0..15
    int lane = tid & 63;
    int quad = lane >> 4;
    int lnib = lane & 15;
    int i0   = blockIdx.x * 32;
    int koff = (quad & 1) * 8;

    const unsigned short* ab = (quad < 2 ? rawh : rawl) + (size_t)(i0 + lnib) * 16 + koff;
    bf16x8 afrag0 = *(const bf16x8*)ab;
    bf16x8 afrag1 = *(const bf16x8*)(ab + 16 * 16);

    float sqi[8];
    #pragma unroll
    for (int r = 0; r < 4; ++r) {
        sqi[r]   = sq[i0 + quad * 4 + r];
        sqi[4+r] = sq[i0 + quad * 4 + r + 16];
    }

    unsigned s0[8], s1[8];     // per-row 2 smallest keys in this slice (s0 <= s1)
    #pragma unroll
    for (int r = 0; r < 8; ++r) { s0[r] = 0xFFFFFFFFu; s1[r] = 0xFFFFFFFFu; }

    // ---- phase 1: 1024 j-tiles over 16 waves, 2-tile ILP (t, t+16; stride 32)
    for (int t = wave; t < B_N / 16; t += 32) {
        int jA = t * 16 + lnib;
        int jB = jA + 256;            // tile t+16
        bf16x8 bhA = *(const bf16x8*)(rawh + (size_t)jA * 16 + koff);
        bf16x8 blA = *(const bf16x8*)(rawl + (size_t)jA * 16 + koff);
        bf16x8 bhB = *(const bf16x8*)(rawh + (size_t)jB * 16 + koff);
        bf16x8 blB = *(const bf16x8*)(rawl + (size_t)jB * 16 + koff);
        float sqjA = sq[jA];
        float sqjB = sq[jB];
        unsigned jmA = 0x80000000u | (unsigned)jA;
        unsigned jmB = 0x80000000u | (unsigned)jB;
        f32x4 a0A = {0,0,0,0}, a1A = {0,0,0,0}, a0B = {0,0,0,0}, a1B = {0,0,0,0};
        a0A = __builtin_amdgcn_mfma_f32_16x16x32_bf16(afrag0, blA, a0A, 0, 0, 0);
        a1A = __builtin_amdgcn_mfma_f32_16x16x32_bf16(afrag1, blA, a1A, 0, 0, 0);
        a0B = __builtin_amdgcn_mfma_f32_16x16x32_bf16(afrag0, blB, a0B, 0, 0, 0);
        a1B = __builtin_amdgcn_mfma_f32_16x16x32_bf16(afrag1, blB, a1B, 0, 0, 0);
        a0A = __builtin_amdgcn_mfma_f32_16x16x32_bf16(afrag0, bhA, a0A, 0, 0, 0);
        a1A = __builtin_amdgcn_mfma_f32_16x16x32_bf16(afrag1, bhA, a1A, 0, 0, 0);
        a0B = __builtin_amdgcn_mfma_f32_16x16x32_bf16(afrag0, bhB, a0B, 0, 0, 0);
        a1B = __builtin_amdgcn_mfma_f32_16x16x32_bf16(afrag1, bhB, a1B, 0, 0, 0);
        // branchless slice-min update (C/D: col=lnib (j), row=quad*4+r)
        #pragma unroll
        for (int r = 0; r < 4; ++r) {
            float d2; unsigned key;
            d2  = (sqi[r] + sqjA) - 2.0f * a0A[r];
            key = (__float_as_uint(d2) & 0x7FFFC000u) | jmA;
            s1[r] = min(s1[r], max(s0[r], key)); s0[r] = min(s0[r], key);
            d2  = (sqi[4+r] + sqjA) - 2.0f * a1A[r];
            key = (__float_as_uint(d2) & 0x7FFFC000u) | jmA;
            s1[4+r] = min(s1[4+r], max(s0[4+r], key)); s0[4+r] = min(s0[4+r], key);
            d2  = (sqi[r] + sqjB) - 2.0f * a0B[r];
            key = (__float_as_uint(d2) & 0x7FFFC000u) | jmB;
            s1[r] = min(s1[r], max(s0[r], key)); s0[r] = min(s0[r], key);
            d2  = (sqi[4+r] + sqjB) - 2.0f * a1B[r];
            key = (__float_as_uint(d2) & 0x7FFFC000u) | jmB;
            s1[4+r] = min(s1[4+r], max(s0[4+r], key)); s0[4+r] = min(s0[4+r], key);
        }
    }

    // ---- phase 2: two 16-row groups; writeout -> per-row wave bisection -> 25 neighbors
    unsigned long long ltm = (1ull << lane) - 1ull;
    for (int g = 0; g < 2; ++g) {
        __syncthreads();   // g=0: no-op hazard; g=1: keyS reads of group 0 complete
        #pragma unroll
        for (int r = 0; r < 4; ++r) {
            int rloc = quad * 4 + r;
            int base = rloc * SCAP + wave * 32 + lnib * 2;
            keyS[base]     = s0[r + 4*g];
            keyS[base + 1] = s1[r + 4*g];
        }
        __syncthreads();

        // wave w handles row w of this group
        int m  = g * 16 + wave;          // row within block
        int pt = i0 + m;                 // global row
        unsigned kl[SMAXL];
        #pragma unroll
        for (int tt = 0; tt < SMAXL; ++tt)
            kl[tt] = keyS[wave * SCAP + tt * 64 + lane];

        // bisect: smallest T26 with count(<= T26) >= 26 (keys distinct via j bits)
        unsigned lo = 0x80000000u, hi = 0xFFFFFFFFu;
        for (int it = 0; it < 32 && lo < hi; ++it) {
            unsigned mid = lo + ((hi - lo) >> 1);
            unsigned cc = 0;
            #pragma unroll
            for (int tt = 0; tt < SMAXL; ++tt)
                cc += (unsigned)__builtin_popcountll(__ballot(kl[tt] <= mid));
            if (cc >= K_NBR + 1) hi = mid; else lo = mid + 1;
        }
        unsigned T26 = hi;

        // collect <= T26, skipping self (low 14 bits == pt)
        int base = 0;
        #pragma unroll
        for (int tt = 0; tt < SMAXL; ++tt) {
            bool c = (kl[tt] <= T26) && ((kl[tt] & 0x3FFFu) != (unsigned)pt);
            unsigned long long mk = __ballot(c);
            if (c) {
                int pos = base + __builtin_popcountll(mk & ltm);
                if (pos < K_NBR) nbrW[wave][pos] = (int)(kl[tt] & 0x3FFFu);
            }
            base += __builtin_popcountll(mk);
        }
        if (lane == 0) {
            int got = base < K_NBR ? base : K_NBR;
            int pad = (got > 0) ? nbrW[wave][0] : pt;
            for (int q = got; q < K_NBR; ++q) nbrW[wave][q] = pad;
        }
        if (lane < K_NBR) nbrG[(size_t)pt * K_NBR + lane] = (unsigned)nbrW[wave][lane];
    }
}

// ---------------------------------------------------------------- eig: MFMA trace, 5 squarings (C^32)
__global__ __launch_bounds__(256) void eig_kernel(const unsigned short* __restrict__ lath,
                                                  const unsigned short* __restrict__ latl,
                                                  const unsigned short* __restrict__ rawh,
                                                  const unsigned short* __restrict__ rawl,
                                                  const unsigned* __restrict__ nbrG,
                                                  float* __restrict__ part) {
    __shared__ unsigned short MS[4][2][2][32 * EPAD];  // [wave][comm][h/l]; rows 25..31 zeroed
    __shared__ unsigned short CH[4][2][32 * EPAD];     // [wave][comm]; rows 0..15 hi, 16..31 lo
    __shared__ float psum[4];

    int wave = threadIdx.x >> 6;
    int lane = threadIdx.x & 63;
    int quad = lane >> 4;
    int lnib = lane & 15;
    int pt   = blockIdx.x * 4 + wave;

    {
        int comm = lane >> 5;
        int row  = lane & 31;
        uint2* dh = (uint2*)&MS[wave][comm][0][row * EPAD];
        uint2* dl = (uint2*)&MS[wave][comm][1][row * EPAD];
        if (row < K_NBR) {
            int n = (int)nbrG[(size_t)pt * K_NBR + row];
            const uint2* sh = (const uint2*)((comm ? rawh : lath) + (size_t)n * 16);
            const uint2* sl = (const uint2*)((comm ? rawl : latl) + (size_t)n * 16);
            dh[0] = sh[0]; dh[1] = sh[1]; dh[2] = sh[2]; dh[3] = sh[3];
            dl[0] = sl[0]; dl[1] = sl[1]; dl[2] = sl[2]; dl[3] = sl[3];
        } else {
            uint2 z = make_uint2(0u, 0u);
            dh[0] = z; dh[1] = z; dh[2] = z; dh[3] = z;
            dl[0] = z; dl[1] = z; dl[2] = z; dl[3] = z;
        }
    }
    __syncthreads();

    bf16x8 ones;
    #pragma unroll
    for (int j = 0; j < 8; ++j) ones[j] = (short)0x3F80;

    const unsigned short* Mzh = &MS[wave][0][0][0];
    const unsigned short* Mzl = &MS[wave][0][1][0];
    const unsigned short* Mxh = &MS[wave][1][0][0];
    const unsigned short* Mxl = &MS[wave][1][1][0];

    bf16x8 fzh, fzl, fxh, fxl;
    #pragma unroll
    for (int j = 0; j < 8; ++j) {
        int k = quad * 8 + j;
        fzh[j] = (short)Mzh[k * EPAD + lnib];
        fzl[j] = (short)Mzl[k * EPAD + lnib];
        fxh[j] = (short)Mxh[k * EPAD + lnib];
        fxl[j] = (short)Mxl[k * EPAD + lnib];
    }

    f32x4 mz = {0.f,0.f,0.f,0.f}, mx = {0.f,0.f,0.f,0.f};
    mz = __builtin_amdgcn_mfma_f32_16x16x32_bf16(fzh, fzh, mz, 0, 0, 0);
    mx = __builtin_amdgcn_mfma_f32_16x16x32_bf16(fxh, fxh, mx, 0, 0, 0);
    mz = __builtin_amdgcn_mfma_f32_16x16x32_bf16(fzh, fzl, mz, 0, 0, 0);
    mx = __builtin_amdgcn_mfma_f32_16x16x32_bf16(fxh, fxl, mx, 0, 0, 0);
    mz = __builtin_amdgcn_mfma_f32_16x16x32_bf16(fzl, fzh, mz, 0, 0, 0);
    mx = __builtin_amdgcn_mfma_f32_16x16x32_bf16(fxl, fxh, mx, 0, 0, 0);
    f32x4 dz1 = {0.f,0.f,0.f,0.f}, dx1 = {0.f,0.f,0.f,0.f};
    dz1 = __builtin_amdgcn_mfma_f32_16x16x32_bf16(fzh, ones, dz1, 0, 0, 0);
    dx1 = __builtin_amdgcn_mfma_f32_16x16x32_bf16(fxh, ones, dx1, 0, 0, 0);
    dz1 = __builtin_amdgcn_mfma_f32_16x16x32_bf16(fzl, ones, dz1, 0, 0, 0);
    dx1 = __builtin_amdgcn_mfma_f32_16x16x32_bf16(fxl, ones, dx1, 0, 0, 0);
    f32x4 dz2 = {0.f,0.f,0.f,0.f}, dx2 = {0.f,0.f,0.f,0.f};
    dz2 = __builtin_amdgcn_mfma_f32_16x16x32_bf16(ones, fzh, dz2, 0, 0, 0);
    dx2 = __builtin_amdgcn_mfma_f32_16x16x32_bf16(ones, fxh, dx2, 0, 0, 0);
    dz2 = __builtin_amdgcn_mfma_f32_16x16x32_bf16(ones, fzl, dz2, 0, 0, 0);
    dx2 = __builtin_amdgcn_mfma_f32_16x16x32_bf16(ones, fxl, dx2, 0, 0, 0);

    f32x4 az, ax;
    #pragma unroll
    for (int r = 0; r < 4; ++r) {
        az[r] = mz[r] - dz1[r] * dz2[r] * 0.04f;
        ax[r] = mx[r] - dx1[r] * dx2[r] * 0.04f;
    }

    bool dg = (quad == (lnib >> 2));

    {
        float tz = dg ? az[lnib & 3] : 0.0f;
        float tx = dg ? ax[lnib & 3] : 0.0f;
        #pragma unroll
        for (int off = 1; off < 64; off <<= 1) {
            tz += __shfl_xor(tz, off, 64);
            tx += __shfl_xor(tx, off, 64);
        }
        float iz = 1.0f / fmaxf(tz, 1e-30f), ix = 1.0f / fmaxf(tx, 1e-30f);
        #pragma unroll
        for (int r = 0; r < 4; ++r) { az[r] *= iz; ax[r] *= ix; }
    }

    unsigned short* Bz = &CH[wave][0][0];
    unsigned short* Bx = &CH[wave][1][0];
    for (int s = 0; s < 5; ++s) {     // C^32
        #pragma unroll
        for (int r = 0; r < 4; ++r) {
            int row = quad * 4 + r;
            unsigned short zh = f2bf(az[r]);
            unsigned short xh = f2bf(ax[r]);
            Bz[row * EPAD + lnib]        = zh;
            Bx[row * EPAD + lnib]        = xh;
            Bz[(row + 16) * EPAD + lnib] = f2bf(az[r] - bf2f(zh));
            Bx[(row + 16) * EPAD + lnib] = f2bf(ax[r] - bf2f(xh));
        }
        bf16x8 fz, gz, fx, gx;
        #pragma unroll
        for (int j = 0; j < 8; ++j) {
            int k  = quad * 8 + j;
            int ks = (k + 16) & 31;
            fz[j] = (short)Bz[k  * EPAD + lnib];
            gz[j] = (short)Bz[ks * EPAD + lnib];
            fx[j] = (short)Bx[k  * EPAD + lnib];
            gx[j] = (short)Bx[ks * EPAD + lnib];
        }
        f32x4 nz = {0.f,0.f,0.f,0.f}, nx = {0.f,0.f,0.f,0.f};
        nz = __builtin_amdgcn_mfma_f32_16x16x32_bf16(fz, fz, nz, 0, 0, 0);
        nx = __builtin_amdgcn_mfma_f32_16x16x32_bf16(fx, fx, nx, 0, 0, 0);
        nz = __builtin_amdgcn_mfma_f32_16x16x32_bf16(fz, gz, nz, 0, 0, 0);
        nx = __builtin_amdgcn_mfma_f32_16x16x32_bf16(fx, gx, nx, 0, 0, 0);
        if (s == 2) {
            float tz = dg ? nz[lnib & 3] : 0.0f;
            float tx = dg ? nx[lnib & 3] : 0.0f;
            #pragma unroll
            for (int off = 1; off < 64; off <<= 1) {
                tz += __shfl_xor(tz, off, 64);
                tx += __shfl_xor(tx, off, 64);
            }
            float iz = 1.0f / fmaxf(tz, 1e-30f), ix = 1.0f / fmaxf(tx, 1e-30f);
            #pragma unroll
            for (int r = 0; r < 4; ++r) { az[r] = nz[r] * iz; ax[r] = nx[r] * ix; }
        } else {
            #pragma unroll
            for (int r = 0; r < 4; ++r) { az[r] = nz[r]; ax[r] = nx[r]; }
        }
    }

    float tz = dg ? az[lnib & 3] : 0.0f;
    float tx = dg ? ax[lnib & 3] : 0.0f;
    float dt = az[0]*ax[0] + az[1]*ax[1] + az[2]*ax[2] + az[3]*ax[3];
    #pragma unroll
    for (int off = 1; off < 64; off <<= 1) {
        tz += __shfl_xor(tz, off, 64);
        tx += __shfl_xor(tx, off, 64);
        dt += __shfl_xor(dt, off, 64);
    }
    if (lane == 0) psum[wave] = dt / fmaxf(tz * tx, 1e-30f);
    __syncthreads();
    if (threadIdx.x == 0)
        part[blockIdx.x] = psum[0] + psum[1] + psum[2] + psum[3];   // plain store, no atomic
}

// ---------------------------------------------------------------- final: reduce partials + combine
__global__ __launch_bounds__(256) void final_kernel(const float* __restrict__ accum,
                                                    const float* __restrict__ part,
                                                    float* __restrict__ out) {
    __shared__ float ws[4];
    int tid = threadIdx.x;
    float s = 0.0f;
    for (int i = tid; i < NPART; i += 256) s += part[i];
    #pragma unroll
    for (int off = 32; off >= 1; off >>= 1) s += __shfl_down(s, off, 64);
    if ((tid & 63) == 0) ws[tid >> 6] = s;
    __syncthreads();
    if (tid == 0) {
        float dot2  = ws[0] + ws[1] + ws[2] + ws[3];
        float recon = accum[0] * (1.0f / (float)(B_N * D_DIM));
        float tsa   = 2.0f - 2.0f * (dot2 * (1.0f / (float)B_N));
        out[0] = recon + 0.1f * tsa;
    }
}

extern "C" void kernel_launch(void* const* d_in, const int* in_sizes, int n_in,
                              void* d_out, int out_size, void* d_ws, size_t ws_size,
                              hipStream_t stream) {
    const float* outputs = (const float*)d_in[0];
    const float* targets = (const float*)d_in[1];
    const float* latent  = (const float*)d_in[2];
    const float* raw     = (const float*)d_in[3];

    float* accum         = (float*)d_ws;
    float* sq            = (float*)((char*)d_ws + WS_SQ_OFF);
    unsigned short* rawh = (unsigned short*)((char*)d_ws + WS_RAWH_OFF);
    unsigned short* rawl = (unsigned short*)((char*)d_ws + WS_RAWL_OFF);
    unsigned short* lath = (unsigned short*)((char*)d_ws + WS_LATH_OFF);
    unsigned short* latl = (unsigned short*)((char*)d_ws + WS_LATL_OFF);
    unsigned* nbrG       = (unsigned*)((char*)d_ws + WS_NBR_OFF);
    float* part          = (float*)((char*)d_ws + WS_PART_OFF);

    const float4* rawv = (const float4*)raw;
    const float4* latv = (const float4*)latent;

    hipMemsetAsync(d_ws, 0, 256, stream);  // zero accum
    prep_kernel<<<B_N / 256, 256, 0, stream>>>(rawv, latv, (const float4*)outputs,
                                               (const float4*)targets, sq, rawh, rawl,
                                               lath, latl, accum);
    scan_kernel<<<B_N / 32, 1024, 0, stream>>>(rawh, rawl, sq, nbrG);
    eig_kernel<<<B_N / 4, 256, 0, stream>>>(lath, latl, rawh, rawl, nbrG, part);
    final_kernel<<<1, 256, 0, stream>>>(accum, part, (float*)d_out);
}